// Round 8
// baseline (2222.321 us; speedup 1.0000x reference)
//
#include <hip/hip_runtime.h>
#include <math.h>

#define Bx 16
#define Cx 64
#define Hx 128
#define Wx 128
#define HWx (Hx * Wx)

#define TW 32
#define TH 8
#define CCH 8
#define HALO_W (TW + 2)
#define HALO_H (TH + 2)
#define CPLANE (HALO_H * HALO_W)          // 340
#define CHUNK_ELEMS (CCH * CPLANE)        // 2720
#define NPF 11                            // ceil(2720/256); sx padded to 11*256=2816
#define SX_PAD (NPF * 256)                // 2816
#define NCHUNK (Cx / CCH)                 // 8

// workspace layout (float offsets)
#define WS_CWT   0                         // cwT[c*64+o]            4096
#define WS_GPACK 4096                      // gpack12[c*96+rg*12+k]  6144  (rg=r*2+g)
#define WS_KERN  10240                     // per-b [c*36+k*4+g]     16*2304
#define WS_ATT   47104                     // per-b [c*4+r]          16*256
#define WS_ZERO  51200                     // 64 zero floats (OOB redirect page)

// async global->LDS, zero VGPR footprint (size must be a literal)
#define GLD_LDS(gp, lp, sz)                                                        \
    __builtin_amdgcn_global_load_lds(                                              \
        (const __attribute__((address_space(1))) void*)(gp),                       \
        (__attribute__((address_space(3))) void*)(lp), sz, 0, 0)

// ---------------- prep: hypernetwork + weight repacking ----------------
__global__ __launch_bounds__(256)
void da_prep(const float* __restrict__ x_deg,
             const float* __restrict__ kw1,
             const float* __restrict__ kw2,
             const float* __restrict__ convw,
             const float* __restrict__ ca_w1,
             const float* __restrict__ ca_w2,
             const float* __restrict__ g1w,
             const float* __restrict__ g2w,
             float* __restrict__ ws)
{
    const int b = blockIdx.x;
    const int tid = threadIdx.x;

    if (b == Bx) {
        for (int i = tid; i < 4096; i += 256) {           // cwT[c*64+o] = convw[o*64+c]
            const int o = i >> 6, c = i & 63;
            ws[WS_CWT + c * 64 + o] = convw[o * 64 + c];
        }
        for (int i = tid; i < 6144; i += 256) {           // gpack12[c][rg=r*2+g][12]
            const int c = i / 96;
            int rem = i - c * 96;
            const int rg = rem / 12;
            const int k  = rem - rg * 12;
            const int r = rg >> 1;
            const int g = rg & 1;
            const float* src = g ? g2w : g1w;
            ws[WS_GPACK + i] = (k < 9) ? src[(r * Cx + c) * 9 + k] : 0.f;
        }
        if (tid < 64) ws[WS_ZERO + tid] = 0.f;            // OOB zero page
        return;
    }

    __shared__ float h1[16];
    __shared__ float a1[16];
    if (tid < 32) {
        const int j = tid & 15;
        const float* wsrc = (tid < 16) ? (kw1 + j * Cx) : (ca_w1 + j * Cx);
        float acc = 0.f;
        #pragma unroll 8
        for (int c = 0; c < Cx; ++c) acc = fmaf(x_deg[b * Cx + c], wsrc[c], acc);
        acc = acc > 0.f ? acc : 0.1f * acc;               // leaky_relu 0.1
        if (tid < 16) h1[j] = acc; else a1[j] = acc;
    }
    __syncthreads();

    for (int o4 = tid; o4 < 4 * 576; o4 += 256) {
        const int g = o4 / 576;
        const int o = o4 - g * 576;
        float acc = 0.f;
        #pragma unroll
        for (int i = 0; i < 4; ++i)
            acc = fmaf(h1[g * 4 + i], kw2[(g * 576 + o) * 4 + i], acc);
        const int c = o / 9;
        const int k = o - c * 9;
        ws[WS_KERN + b * 2304 + c * 36 + k * 4 + g] = acc;
    }
    {
        const int r = tid >> 6;
        const int c = tid & 63;
        float acc = 0.f;
        #pragma unroll
        for (int i = 0; i < 4; ++i)
            acc = fmaf(a1[r * 4 + i], ca_w2[(r * Cx + c) * 4 + i], acc);
        ws[WS_ATT + b * 256 + c * 4 + r] = 1.f / (1.f + expf(-acc));
    }
}

// ---------------- main fused kernel ----------------
// Staging uses global_load_lds exclusively: loads never touch VGPRs, so
// overlapping next-chunk staging with the y[64] compute body cannot trigger
// the alloca-spill (rounds 2-5,7 failure mode). Compute bodies byte-identical
// to round 6 (proven clean: 96 VGPR, WRITE=64MB, absmax 7.8e-3).
__global__ __launch_bounds__(256, 2)
void da_main(const float* __restrict__ x0,
             const float* __restrict__ ws,
             const float* __restrict__ g1b,
             const float* __restrict__ g2b,
             const float* __restrict__ convb,
             float* __restrict__ out)
{
    const int b  = blockIdx.z;
    const int h0 = blockIdx.y * TH;
    const int w0 = blockIdx.x * TW;
    const int tid = threadIdx.x;
    const int tx = tid & (TW - 1);
    const int ty = tid >> 5;

    __shared__ float sx[2][SX_PAD];                   // ping-pong x chunk (halo, padded)
    __shared__ __align__(16) float sgp[6144];         // guide weights [c][rg][12]
    __shared__ __align__(16) float scw[4096];         // cwT [c][o]
    __shared__ __align__(16) float skern[2304];       // [c][k][r]
    __shared__ __align__(16) float satt[256];         // [c][r]
    // LDS ~72 KB -> 2 blocks/CU

    const float* xb = x0 + (size_t)b * Cx * HWx;
    const float* zp = ws + WS_ZERO;                   // zero page for OOB lanes

    // async staging of one x-chunk: 11 width-4 calls, per-lane source address,
    // linear LDS dest (base + lane*4). Zero register residue.
    auto STAGE = [&](int nch, float* dbuf) {
        const float* srcb = xb + (size_t)nch * CCH * HWx;
        #pragma unroll
        for (int i = 0; i < NPF; ++i) {
            const int e = tid + i * 256;
            const int cc  = e / CPLANE;
            const int rem = e - cc * CPLANE;
            const int row = rem / HALO_W;
            const int col = rem - row * HALO_W;
            const int gh = h0 - 1 + row;
            const int gw = w0 - 1 + col;
            const float* sp = zp;
            if (e < CHUNK_ELEMS && (unsigned)gh < Hx && (unsigned)gw < Wx)
                sp = srcb + cc * HWx + gh * Wx + gw;
            GLD_LDS(sp, dbuf + e, 4);
        }
    };

    // --- prologue: weights (width-16 async) + chunk 0 ---
    {
        const float* gsrc = ws + WS_GPACK;
        #pragma unroll
        for (int j = 0; j < 6; ++j)
            GLD_LDS(gsrc + j * 1024 + tid * 4, sgp + j * 1024 + tid * 4, 16);
        const float* csrc = ws + WS_CWT;
        #pragma unroll
        for (int j = 0; j < 4; ++j)
            GLD_LDS(csrc + j * 1024 + tid * 4, scw + j * 1024 + tid * 4, 16);
        const float* ksrc = ws + WS_KERN + b * 2304;
        #pragma unroll
        for (int j = 0; j < 2; ++j)
            GLD_LDS(ksrc + j * 1024 + tid * 4, skern + j * 1024 + tid * 4, 16);
        GLD_LDS(ksrc + 2048 + tid, skern + 2048 + tid, 4);
        GLD_LDS(ws + WS_ATT + b * 256 + tid, satt + tid, 4);
        STAGE(0, sx[0]);
    }
    __syncthreads();

    // ================= PASS 1: guide convs -> argmax =================
    float ga[8];
    #pragma unroll
    for (int r = 0; r < 4; ++r) { ga[r] = g1b[r]; ga[4 + r] = g2b[r]; }

    #pragma unroll 1
    for (int ch = 0; ch < NCHUNK; ++ch) {
        const int buf = ch & 1;
        STAGE((ch + 1) & (NCHUNK - 1), sx[buf ^ 1]);  // ch==7 stages chunk 0 for pass 2

        float pg[8] = {0.f, 0.f, 0.f, 0.f, 0.f, 0.f, 0.f, 0.f};
        #pragma unroll
        for (int cc = 0; cc < CCH; ++cc) {
            const int c = ch * CCH + cc;
            float n[9];
            #pragma unroll
            for (int kh = 0; kh < 3; ++kh)
                #pragma unroll
                for (int kw = 0; kw < 3; ++kw)
                    n[kh * 3 + kw] = sx[buf][cc * CPLANE + (ty + kh) * HALO_W + (tx + kw)];
            const float4* gpv = (const float4*)(sgp + c * 96);   // uniform b128 broadcast
            #pragma unroll
            for (int rg = 0; rg < 8; ++rg) {          // rg = r*2+g
                const float4 q0 = gpv[rg * 3 + 0];
                const float4 q1 = gpv[rg * 3 + 1];
                const float4 q2 = gpv[rg * 3 + 2];
                float s = 0.f;                        // k-ascending, bit-identical chain
                s = fmaf(n[0], q0.x, s); s = fmaf(n[1], q0.y, s); s = fmaf(n[2], q0.z, s);
                s = fmaf(n[3], q0.w, s); s = fmaf(n[4], q1.x, s); s = fmaf(n[5], q1.y, s);
                s = fmaf(n[6], q1.z, s); s = fmaf(n[7], q1.w, s); s = fmaf(n[8], q2.x, s);
                pg[(rg >> 1) + (rg & 1) * 4] += s;    // static index (unrolled rg)
            }
        }
        #pragma unroll
        for (int i = 0; i < 8; ++i) ga[i] += pg[i];

        __syncthreads();   // drains vmcnt(0): next chunk resident before flip
    }

    int r1 = 0, r2 = 0;
    {
        float m = ga[0];
        #pragma unroll
        for (int r = 1; r < 4; ++r) if (ga[r] > m) { m = ga[r]; r1 = r; }   // first-max ties
        float m2 = ga[4];
        #pragma unroll
        for (int r = 1; r < 4; ++r) if (ga[4 + r] > m2) { m2 = ga[4 + r]; r2 = r; }
    }

    // ================= PASS 2: routed depthwise + 1x1 =================
    float y[Cx];
    #pragma unroll
    for (int o = 0; o < Cx; ++o) y[o] = 0.f;

    #pragma unroll 1
    for (int ch = 0; ch < NCHUNK; ++ch) {
        const int buf = ch & 1;     // chunk 0 staged into buf 0 by pass-1's last phase
        if (ch < NCHUNK - 1)
            STAGE(ch + 1, sx[buf ^ 1]);

        #pragma unroll
        for (int cc = 0; cc < CCH; ++cc) {
            const int c = ch * CCH + cc;
            float n[9];
            #pragma unroll
            for (int kh = 0; kh < 3; ++kh)
                #pragma unroll
                for (int kw = 0; kw < 3; ++kw)
                    n[kh * 3 + kw] = sx[buf][cc * CPLANE + (ty + kh) * HALO_W + (tx + kw)];

            float dw = 0.f;
            #pragma unroll
            for (int k = 0; k < 9; ++k)
                dw = fmaf(n[k], skern[c * 36 + k * 4 + r1], dw);
            const float routed = dw > 0.f ? dw : 0.1f * dw;

            const float4* cwv = (const float4*)(scw + c * 64);   // uniform b128 broadcast
            #pragma unroll
            for (int q = 0; q < 16; ++q) {            // y statically indexed only
                const float4 w4 = cwv[q];
                y[q * 4 + 0] = fmaf(w4.x, routed, y[q * 4 + 0]);
                y[q * 4 + 1] = fmaf(w4.y, routed, y[q * 4 + 1]);
                y[q * 4 + 2] = fmaf(w4.z, routed, y[q * 4 + 2]);
                y[q * 4 + 3] = fmaf(w4.w, routed, y[q * 4 + 3]);
            }
        }

        if (ch < NCHUNK - 1)
            __syncthreads();
    }

    // --- epilogue: bias + CA branch (x center re-read) + store ---
    const int hh = h0 + ty;
    const int ww = w0 + tx;
    float* op = out + (size_t)b * Cx * HWx + hh * Wx + ww;
    const float* xp = xb + hh * Wx + ww;
    #pragma unroll
    for (int o = 0; o < Cx; ++o) {
        const float v = y[o] + convb[o] + xp[(size_t)o * HWx] * satt[o * 4 + r2];
        op[(size_t)o * HWx] = v;
    }
}

extern "C" void kernel_launch(void* const* d_in, const int* in_sizes, int n_in,
                              void* d_out, int out_size, void* d_ws, size_t ws_size,
                              hipStream_t stream) {
    const float* x0     = (const float*)d_in[0];
    const float* x_deg  = (const float*)d_in[1];
    const float* kw1    = (const float*)d_in[2];
    const float* kw2    = (const float*)d_in[3];
    const float* convw  = (const float*)d_in[4];
    const float* convb  = (const float*)d_in[5];
    const float* ca_w1  = (const float*)d_in[6];
    const float* ca_w2  = (const float*)d_in[7];
    const float* g1w    = (const float*)d_in[8];
    const float* g1b    = (const float*)d_in[9];
    const float* g2w    = (const float*)d_in[10];
    const float* g2b    = (const float*)d_in[11];
    float* outp = (float*)d_out;
    float* wsf  = (float*)d_ws;

    da_prep<<<Bx + 1, 256, 0, stream>>>(x_deg, kw1, kw2, convw, ca_w1, ca_w2,
                                        g1w, g2w, wsf);

    dim3 grid(Wx / TW, Hx / TH, Bx);   // 4 x 16 x 16 = 1024 blocks
    da_main<<<grid, 256, 0, stream>>>(x0, wsf, g1b, g2b, convb, outp);
}

// Round 9
// 261.637 us; speedup vs baseline: 8.4939x; 8.4939x over previous
//
#include <hip/hip_runtime.h>
#include <math.h>

#define Bx 16
#define Cx 64
#define Hx 128
#define Wx 128
#define HWx (Hx * Wx)

#define TW 32
#define TH 8
#define CCH 8
#define HALO_W (TW + 2)
#define HALO_H (TH + 2)
#define CPLANE (HALO_H * HALO_W)          // 340
#define CHUNK_ELEMS (CCH * CPLANE)        // 2720
#define NCHUNK (Cx / CCH)                 // 8

// workspace layout (float offsets)
#define WS_CWT   0                         // cwT[c*64+o]            4096
#define WS_GPACK 4096                      // gpack12[c*96+rg*12+k]  6144  (rg=r*2+g)
#define WS_KERN  10240                     // per-b [c*36+k*4+g]     16*2304
#define WS_ATT   47104                     // per-b [c*4+r]          16*256

// ---------------- prep: hypernetwork + weight repacking (unchanged, passing) ----------------
__global__ __launch_bounds__(256)
void da_prep(const float* __restrict__ x_deg,
             const float* __restrict__ kw1,
             const float* __restrict__ kw2,
             const float* __restrict__ convw,
             const float* __restrict__ ca_w1,
             const float* __restrict__ ca_w2,
             const float* __restrict__ g1w,
             const float* __restrict__ g2w,
             float* __restrict__ ws)
{
    const int b = blockIdx.x;
    const int tid = threadIdx.x;

    if (b == Bx) {
        for (int i = tid; i < 4096; i += 256) {           // cwT[c*64+o] = convw[o*64+c]
            const int o = i >> 6, c = i & 63;
            ws[WS_CWT + c * 64 + o] = convw[o * 64 + c];
        }
        for (int i = tid; i < 6144; i += 256) {           // gpack12[c][rg=r*2+g][12]
            const int c = i / 96;
            int rem = i - c * 96;
            const int rg = rem / 12;
            const int k  = rem - rg * 12;
            const int r = rg >> 1;
            const int g = rg & 1;
            const float* src = g ? g2w : g1w;
            ws[WS_GPACK + i] = (k < 9) ? src[(r * Cx + c) * 9 + k] : 0.f;
        }
        return;
    }

    __shared__ float h1[16];
    __shared__ float a1[16];
    if (tid < 32) {
        const int j = tid & 15;
        const float* wsrc = (tid < 16) ? (kw1 + j * Cx) : (ca_w1 + j * Cx);
        float acc = 0.f;
        #pragma unroll 8
        for (int c = 0; c < Cx; ++c) acc = fmaf(x_deg[b * Cx + c], wsrc[c], acc);
        acc = acc > 0.f ? acc : 0.1f * acc;               // leaky_relu 0.1
        if (tid < 16) h1[j] = acc; else a1[j] = acc;
    }
    __syncthreads();

    for (int o4 = tid; o4 < 4 * 576; o4 += 256) {
        const int g = o4 / 576;
        const int o = o4 - g * 576;
        float acc = 0.f;
        #pragma unroll
        for (int i = 0; i < 4; ++i)
            acc = fmaf(h1[g * 4 + i], kw2[(g * 576 + o) * 4 + i], acc);
        const int c = o / 9;
        const int k = o - c * 9;
        ws[WS_KERN + b * 2304 + c * 36 + k * 4 + g] = acc;
    }
    {
        const int r = tid >> 6;
        const int c = tid & 63;
        float acc = 0.f;
        #pragma unroll
        for (int i = 0; i < 4; ++i)
            acc = fmaf(a1[r * 4 + i], ca_w2[(r * Cx + c) * 4 + i], acc);
        ws[WS_ATT + b * 256 + c * 4 + r] = 1.f / (1.f + expf(-acc));
    }
}

// ---------------- main fused kernel: round-6 body + LDS overlay for 4 blocks/CU ----------------
// Compiler law (falsified-mechanism count: 5): staging interleaved with the
// y[64] compute body => alloca demoted to scratch, GBs of spill traffic.
// Therefore NO pipelining. Staging strictly phase-separated by barriers
// (round-6 structure, proven 96 VGPR / WRITE=64MB / absmax 7.8e-3).
// Single lever here: pass-1 weights (24KB) and pass-2 weights (26KB) overlay
// in one LDS union, restaged between passes -> 62KB -> 37.5KB -> 4 blocks/CU.
__global__ __launch_bounds__(256, 2)
void da_main(const float* __restrict__ x0,
             const float* __restrict__ ws,
             const float* __restrict__ g1b,
             const float* __restrict__ g2b,
             const float* __restrict__ convb,
             float* __restrict__ out)
{
    const int b  = blockIdx.z;
    const int h0 = blockIdx.y * TH;
    const int w0 = blockIdx.x * TW;
    const int tid = threadIdx.x;
    const int tx = tid & (TW - 1);
    const int ty = tid >> 5;

    // pass 1: swts[0..6144)  = sgp   [c][rg][12]
    // pass 2: swts[0..4096)  = scw   [c][o]
    //         swts[4096..6400) = skern [c][k][r]
    //         swts[6400..6656) = satt  [c][r]
    __shared__ __align__(16) float swts[6656];        // 26.0 KB (union)
    __shared__ __align__(16) float sx[CHUNK_ELEMS];   // 10.6 KB x chunk (halo)
    // total ~37.5 KB -> 4 blocks/CU

    const float* xb  = x0 + (size_t)b * Cx * HWx;
    const float* kws = ws + WS_KERN + b * 2304;
    const float* aws = ws + WS_ATT  + b * 256;

    // --- prologue: pass-1 guide weights via contiguous float4 copies ---
    {
        const float4* s4 = (const float4*)(ws + WS_GPACK);
        float4* d4 = (float4*)swts;
        #pragma unroll 1
        for (int j = 0; j < 6; ++j) d4[tid + j * 256] = s4[tid + j * 256];
    }

    // ================= PASS 1: guide convs -> argmax =================
    float ga[8];
    #pragma unroll
    for (int r = 0; r < 4; ++r) { ga[r] = g1b[r]; ga[4 + r] = g2b[r]; }

    #pragma unroll 1
    for (int ch = 0; ch < NCHUNK; ++ch) {
        __syncthreads();
        #pragma unroll 1
        for (int e = tid; e < CHUNK_ELEMS; e += 256) {   // round-6 inline staging
            const int cc  = e / CPLANE;
            const int rem = e - cc * CPLANE;
            const int row = rem / HALO_W;
            const int col = rem - row * HALO_W;
            const int gh = h0 - 1 + row;
            const int gw = w0 - 1 + col;
            float v = 0.f;
            if ((unsigned)gh < Hx && (unsigned)gw < Wx)
                v = xb[(size_t)(ch * CCH + cc) * HWx + gh * Wx + gw];
            sx[e] = v;
        }
        __syncthreads();

        float pg[8] = {0.f, 0.f, 0.f, 0.f, 0.f, 0.f, 0.f, 0.f};
        #pragma unroll
        for (int cc = 0; cc < CCH; ++cc) {
            const int c = ch * CCH + cc;
            float n[9];
            #pragma unroll
            for (int kh = 0; kh < 3; ++kh)
                #pragma unroll
                for (int kw = 0; kw < 3; ++kw)
                    n[kh * 3 + kw] = sx[cc * CPLANE + (ty + kh) * HALO_W + (tx + kw)];
            const float4* gpv = (const float4*)(swts + c * 96);  // uniform b128 broadcast
            #pragma unroll
            for (int rg = 0; rg < 8; ++rg) {          // rg = r*2+g
                const float4 q0 = gpv[rg * 3 + 0];
                const float4 q1 = gpv[rg * 3 + 1];
                const float4 q2 = gpv[rg * 3 + 2];
                float s = 0.f;                        // k-ascending, bit-identical chain
                s = fmaf(n[0], q0.x, s); s = fmaf(n[1], q0.y, s); s = fmaf(n[2], q0.z, s);
                s = fmaf(n[3], q0.w, s); s = fmaf(n[4], q1.x, s); s = fmaf(n[5], q1.y, s);
                s = fmaf(n[6], q1.z, s); s = fmaf(n[7], q1.w, s); s = fmaf(n[8], q2.x, s);
                pg[(rg >> 1) + (rg & 1) * 4] += s;    // static index (unrolled rg)
            }
        }
        #pragma unroll
        for (int i = 0; i < 8; ++i) ga[i] += pg[i];
    }

    int r1 = 0, r2 = 0;
    {
        float m = ga[0];
        #pragma unroll
        for (int r = 1; r < 4; ++r) if (ga[r] > m) { m = ga[r]; r1 = r; }   // first-max ties
        float m2 = ga[4];
        #pragma unroll
        for (int r = 1; r < 4; ++r) if (ga[4 + r] > m2) { m2 = ga[4 + r]; r2 = r; }
    }

    // --- pass transition: overlay-restage pass-2 weights (only r1,r2 live) ---
    __syncthreads();    // all waves done reading guide weights
    {
        const float4* s4 = (const float4*)(ws + WS_CWT);
        float4* d4 = (float4*)swts;                   // scw at 0
        #pragma unroll 1
        for (int j = 0; j < 4; ++j) d4[tid + j * 256] = s4[tid + j * 256];
        const float4* k4 = (const float4*)kws;
        float4* kd4 = (float4*)(swts + 4096);         // skern at 4096
        #pragma unroll 1
        for (int j = 0; j < 2; ++j) kd4[tid + j * 256] = k4[tid + j * 256];
        swts[6144 + tid] = kws[2048 + tid];           // skern tail (256)
        swts[6400 + tid] = aws[tid];                  // satt at 6400
    }
    // visibility: pass-2 loop-top barrier

    // ================= PASS 2: routed depthwise + 1x1 =================
    float y[Cx];
    #pragma unroll
    for (int o = 0; o < Cx; ++o) y[o] = 0.f;

    #pragma unroll 1
    for (int ch = 0; ch < NCHUNK; ++ch) {
        __syncthreads();
        #pragma unroll 1
        for (int e = tid; e < CHUNK_ELEMS; e += 256) {
            const int cc  = e / CPLANE;
            const int rem = e - cc * CPLANE;
            const int row = rem / HALO_W;
            const int col = rem - row * HALO_W;
            const int gh = h0 - 1 + row;
            const int gw = w0 - 1 + col;
            float v = 0.f;
            if ((unsigned)gh < Hx && (unsigned)gw < Wx)
                v = xb[(size_t)(ch * CCH + cc) * HWx + gh * Wx + gw];
            sx[e] = v;
        }
        __syncthreads();

        #pragma unroll
        for (int cc = 0; cc < CCH; ++cc) {
            const int c = ch * CCH + cc;
            float n[9];
            #pragma unroll
            for (int kh = 0; kh < 3; ++kh)
                #pragma unroll
                for (int kw = 0; kw < 3; ++kw)
                    n[kh * 3 + kw] = sx[cc * CPLANE + (ty + kh) * HALO_W + (tx + kw)];

            float dw = 0.f;
            #pragma unroll
            for (int k = 0; k < 9; ++k)
                dw = fmaf(n[k], swts[4096 + c * 36 + k * 4 + r1], dw);
            const float routed = dw > 0.f ? dw : 0.1f * dw;

            const float4* cwv = (const float4*)(swts + c * 64);  // uniform b128 broadcast
            #pragma unroll
            for (int q = 0; q < 16; ++q) {            // y statically indexed only
                const float4 w4 = cwv[q];
                y[q * 4 + 0] = fmaf(w4.x, routed, y[q * 4 + 0]);
                y[q * 4 + 1] = fmaf(w4.y, routed, y[q * 4 + 1]);
                y[q * 4 + 2] = fmaf(w4.z, routed, y[q * 4 + 2]);
                y[q * 4 + 3] = fmaf(w4.w, routed, y[q * 4 + 3]);
            }
        }
    }

    // --- epilogue: bias + CA branch (x center re-read) + store ---
    const int hh = h0 + ty;
    const int ww = w0 + tx;
    float* op = out + (size_t)b * Cx * HWx + hh * Wx + ww;
    const float* xp = xb + hh * Wx + ww;
    #pragma unroll
    for (int o = 0; o < Cx; ++o) {
        const float v = y[o] + convb[o] + xp[(size_t)o * HWx] * swts[6400 + o * 4 + r2];
        op[(size_t)o * HWx] = v;
    }
}

extern "C" void kernel_launch(void* const* d_in, const int* in_sizes, int n_in,
                              void* d_out, int out_size, void* d_ws, size_t ws_size,
                              hipStream_t stream) {
    const float* x0     = (const float*)d_in[0];
    const float* x_deg  = (const float*)d_in[1];
    const float* kw1    = (const float*)d_in[2];
    const float* kw2    = (const float*)d_in[3];
    const float* convw  = (const float*)d_in[4];
    const float* convb  = (const float*)d_in[5];
    const float* ca_w1  = (const float*)d_in[6];
    const float* ca_w2  = (const float*)d_in[7];
    const float* g1w    = (const float*)d_in[8];
    const float* g1b    = (const float*)d_in[9];
    const float* g2w    = (const float*)d_in[10];
    const float* g2b    = (const float*)d_in[11];
    float* outp = (float*)d_out;
    float* wsf  = (float*)d_ws;

    da_prep<<<Bx + 1, 256, 0, stream>>>(x_deg, kw1, kw2, convw, ca_w1, ca_w2,
                                        g1w, g2w, wsf);

    dim3 grid(Wx / TW, Hx / TH, Bx);   // 4 x 16 x 16 = 1024 blocks
    da_main<<<grid, 256, 0, stream>>>(x0, wsf, g1b, g2b, convb, outp);
}

// Round 10
// 172.546 us; speedup vs baseline: 12.8796x; 1.5163x over previous
//
#include <hip/hip_runtime.h>
#include <math.h>

#define Bx 16
#define Cx 64
#define Hx 128
#define Wx 128
#define HWx (Hx * Wx)

#define TW 32
#define TH 8
#define CCH 8
#define HALO_W (TW + 2)
#define HALO_H (TH + 2)
#define CPLANE (HALO_H * HALO_W)          // 340
#define CHUNK_ELEMS (CCH * CPLANE)        // 2720
#define NCHUNK (Cx / CCH)                 // 8

// workspace layout (float offsets)
#define WS_CWT   0                         // cwT[c*64+o]            4096
#define WS_GPACK 4096                      // gpack12[c*96+rg*12+k]  6144  (rg=r*2+g)
#define WS_KERN  10240                     // per-b [c*36+k*4+g]     16*2304
#define WS_ATT   47104                     // per-b [c*4+r]          16*256

// ---------------- prep: hypernetwork + weight repacking (unchanged, passing) ----------------
__global__ __launch_bounds__(256)
void da_prep(const float* __restrict__ x_deg,
             const float* __restrict__ kw1,
             const float* __restrict__ kw2,
             const float* __restrict__ convw,
             const float* __restrict__ ca_w1,
             const float* __restrict__ ca_w2,
             const float* __restrict__ g1w,
             const float* __restrict__ g2w,
             float* __restrict__ ws)
{
    const int b = blockIdx.x;
    const int tid = threadIdx.x;

    if (b == Bx) {
        for (int i = tid; i < 4096; i += 256) {           // cwT[c*64+o] = convw[o*64+c]
            const int o = i >> 6, c = i & 63;
            ws[WS_CWT + c * 64 + o] = convw[o * 64 + c];
        }
        for (int i = tid; i < 6144; i += 256) {           // gpack12[c][rg=r*2+g][12]
            const int c = i / 96;
            int rem = i - c * 96;
            const int rg = rem / 12;
            const int k  = rem - rg * 12;
            const int r = rg >> 1;
            const int g = rg & 1;
            const float* src = g ? g2w : g1w;
            ws[WS_GPACK + i] = (k < 9) ? src[(r * Cx + c) * 9 + k] : 0.f;
        }
        return;
    }

    __shared__ float h1[16];
    __shared__ float a1[16];
    if (tid < 32) {
        const int j = tid & 15;
        const float* wsrc = (tid < 16) ? (kw1 + j * Cx) : (ca_w1 + j * Cx);
        float acc = 0.f;
        #pragma unroll 8
        for (int c = 0; c < Cx; ++c) acc = fmaf(x_deg[b * Cx + c], wsrc[c], acc);
        acc = acc > 0.f ? acc : 0.1f * acc;               // leaky_relu 0.1
        if (tid < 16) h1[j] = acc; else a1[j] = acc;
    }
    __syncthreads();

    for (int o4 = tid; o4 < 4 * 576; o4 += 256) {
        const int g = o4 / 576;
        const int o = o4 - g * 576;
        float acc = 0.f;
        #pragma unroll
        for (int i = 0; i < 4; ++i)
            acc = fmaf(h1[g * 4 + i], kw2[(g * 576 + o) * 4 + i], acc);
        const int c = o / 9;
        const int k = o - c * 9;
        ws[WS_KERN + b * 2304 + c * 36 + k * 4 + g] = acc;
    }
    {
        const int r = tid >> 6;
        const int c = tid & 63;
        float acc = 0.f;
        #pragma unroll
        for (int i = 0; i < 4; ++i)
            acc = fmaf(a1[r * 4 + i], ca_w2[(r * Cx + c) * 4 + i], acc);
        ws[WS_ATT + b * 256 + c * 4 + r] = 1.f / (1.f + expf(-acc));
    }
}

// ---------------- main fused kernel: R9 structure + batched (non-serial) staging ----------------
// Spill law (R2-R5,R7,R8): staging interleaved/overlapped with the y[64]
// compute body => alloca demoted to scratch. So: NO cross-phase pipelining.
// This round only batches loads WITHIN each barrier-delimited staging phase
// (11 named scalar temps, issue-all-then-write-all => 1 latency instead of 11
// serial round-trips), and hoists the div/mod address math to 11 persistent
// named offsets (R1-proven clean pattern).
__global__ __launch_bounds__(256, 2)
void da_main(const float* __restrict__ x0,
             const float* __restrict__ ws,
             const float* __restrict__ g1b,
             const float* __restrict__ g2b,
             const float* __restrict__ convb,
             float* __restrict__ out)
{
    const int b  = blockIdx.z;
    const int h0 = blockIdx.y * TH;
    const int w0 = blockIdx.x * TW;
    const int tid = threadIdx.x;
    const int tx = tid & (TW - 1);
    const int ty = tid >> 5;

    // pass 1: swts[0..6144)   = sgp   [c][rg][12]
    // pass 2: swts[0..4096)   = scw   [c][o]
    //         swts[4096..6400)= skern [c][k][r]
    //         swts[6400..6656)= satt  [c][r]
    __shared__ __align__(16) float swts[6656];        // 26.0 KB (union)
    __shared__ __align__(16) float sx[CHUNK_ELEMS];   // 10.6 KB x chunk (halo)
    // total ~37.5 KB -> 4 blocks/CU

    const float* xb  = x0 + (size_t)b * Cx * HWx;
    const float* kws = ws + WS_KERN + b * 2304;
    const float* aws = ws + WS_ATT  + b * 256;

    // --- per-thread staging offsets, computed ONCE (named ints, no array) ---
    int o0, o1, o2, o3, o4, o5, o6, o7, o8, o9, o10;
    unsigned vmask = 0u;
#define MKOFF(i, oname)                                                        \
    do {                                                                       \
        const int e   = tid + (i) * 256;                                       \
        const int cc  = e / CPLANE;                                            \
        const int rem = e - cc * CPLANE;                                       \
        const int row = rem / HALO_W;                                          \
        const int col = rem - row * HALO_W;                                    \
        const int gh  = h0 - 1 + row;                                          \
        const int gw  = w0 - 1 + col;                                          \
        oname = cc * HWx + gh * Wx + gw;                                       \
        if (e < CHUNK_ELEMS && (unsigned)gh < Hx && (unsigned)gw < Wx)         \
            vmask |= (1u << (i));                                              \
    } while (0)
    MKOFF(0, o0);  MKOFF(1, o1);  MKOFF(2, o2);  MKOFF(3, o3);
    MKOFF(4, o4);  MKOFF(5, o5);  MKOFF(6, o6);  MKOFF(7, o7);
    MKOFF(8, o8);  MKOFF(9, o9);  MKOFF(10, o10);
#undef MKOFF

    // batched staging of one chunk: issue all loads, then all LDS writes
#define STAGE_CHUNK(ch)                                                        \
    do {                                                                       \
        const float* src = xb + (size_t)(ch) * CCH * HWx;                      \
        float v0 = 0.f, v1 = 0.f, v2 = 0.f, v3 = 0.f, v4 = 0.f, v5 = 0.f;     \
        float v6 = 0.f, v7 = 0.f, v8 = 0.f, v9 = 0.f, v10 = 0.f;              \
        if (vmask & 1u)      v0  = src[o0];                                    \
        if (vmask & 2u)      v1  = src[o1];                                    \
        if (vmask & 4u)      v2  = src[o2];                                    \
        if (vmask & 8u)      v3  = src[o3];                                    \
        if (vmask & 16u)     v4  = src[o4];                                    \
        if (vmask & 32u)     v5  = src[o5];                                    \
        if (vmask & 64u)     v6  = src[o6];                                    \
        if (vmask & 128u)    v7  = src[o7];                                    \
        if (vmask & 256u)    v8  = src[o8];                                    \
        if (vmask & 512u)    v9  = src[o9];                                    \
        if (vmask & 1024u)   v10 = src[o10];                                   \
        sx[tid]           = v0;   sx[tid + 256]  = v1;                         \
        sx[tid + 512]     = v2;   sx[tid + 768]  = v3;                         \
        sx[tid + 1024]    = v4;   sx[tid + 1280] = v5;                         \
        sx[tid + 1536]    = v6;   sx[tid + 1792] = v7;                         \
        sx[tid + 2048]    = v8;   sx[tid + 2304] = v9;                         \
        if (tid < CHUNK_ELEMS - 2560) sx[tid + 2560] = v10;                    \
    } while (0)

    // --- prologue: pass-1 guide weights, batched float4 copies ---
    {
        const float4* s4 = (const float4*)(ws + WS_GPACK);
        float4* d4 = (float4*)swts;
        const float4 g0 = s4[tid], g1 = s4[tid + 256], g2 = s4[tid + 512];
        const float4 g3 = s4[tid + 768], g4 = s4[tid + 1024], g5 = s4[tid + 1280];
        d4[tid] = g0; d4[tid + 256] = g1; d4[tid + 512] = g2;
        d4[tid + 768] = g3; d4[tid + 1024] = g4; d4[tid + 1280] = g5;
    }

    // ================= PASS 1: guide convs -> argmax =================
    float ga[8];
    #pragma unroll
    for (int r = 0; r < 4; ++r) { ga[r] = g1b[r]; ga[4 + r] = g2b[r]; }

    #pragma unroll 1
    for (int ch = 0; ch < NCHUNK; ++ch) {
        __syncthreads();
        STAGE_CHUNK(ch);
        __syncthreads();

        float pg[8] = {0.f, 0.f, 0.f, 0.f, 0.f, 0.f, 0.f, 0.f};
        #pragma unroll
        for (int cc = 0; cc < CCH; ++cc) {
            const int c = ch * CCH + cc;
            float n[9];
            #pragma unroll
            for (int kh = 0; kh < 3; ++kh)
                #pragma unroll
                for (int kw = 0; kw < 3; ++kw)
                    n[kh * 3 + kw] = sx[cc * CPLANE + (ty + kh) * HALO_W + (tx + kw)];
            const float4* gpv = (const float4*)(swts + c * 96);  // uniform b128 broadcast
            #pragma unroll
            for (int rg = 0; rg < 8; ++rg) {          // rg = r*2+g
                const float4 q0 = gpv[rg * 3 + 0];
                const float4 q1 = gpv[rg * 3 + 1];
                const float4 q2 = gpv[rg * 3 + 2];
                float s = 0.f;                        // k-ascending, bit-identical chain
                s = fmaf(n[0], q0.x, s); s = fmaf(n[1], q0.y, s); s = fmaf(n[2], q0.z, s);
                s = fmaf(n[3], q0.w, s); s = fmaf(n[4], q1.x, s); s = fmaf(n[5], q1.y, s);
                s = fmaf(n[6], q1.z, s); s = fmaf(n[7], q1.w, s); s = fmaf(n[8], q2.x, s);
                pg[(rg >> 1) + (rg & 1) * 4] += s;    // static index (unrolled rg)
            }
        }
        #pragma unroll
        for (int i = 0; i < 8; ++i) ga[i] += pg[i];
    }

    int r1 = 0, r2 = 0;
    {
        float m = ga[0];
        #pragma unroll
        for (int r = 1; r < 4; ++r) if (ga[r] > m) { m = ga[r]; r1 = r; }   // first-max ties
        float m2 = ga[4];
        #pragma unroll
        for (int r = 1; r < 4; ++r) if (ga[4 + r] > m2) { m2 = ga[4 + r]; r2 = r; }
    }

    // --- pass transition: overlay-restage pass-2 weights (batched) ---
    __syncthreads();    // all waves done reading guide weights
    {
        const float4* s4 = (const float4*)(ws + WS_CWT);
        const float4 c0 = s4[tid], c1 = s4[tid + 256], c2 = s4[tid + 512], c3 = s4[tid + 768];
        const float4* k4 = (const float4*)kws;
        const float4 k0 = k4[tid], k1 = k4[tid + 256];
        const float kt = kws[2048 + tid];
        const float at = aws[tid];
        float4* d4 = (float4*)swts;                   // scw at 0
        d4[tid] = c0; d4[tid + 256] = c1; d4[tid + 512] = c2; d4[tid + 768] = c3;
        float4* kd4 = (float4*)(swts + 4096);         // skern at 4096
        kd4[tid] = k0; kd4[tid + 256] = k1;
        swts[6144 + tid] = kt;                        // skern tail
        swts[6400 + tid] = at;                        // satt
    }
    // visibility: pass-2 loop-top barrier

    // ================= PASS 2: routed depthwise + 1x1 =================
    float y[Cx];
    #pragma unroll
    for (int o = 0; o < Cx; ++o) y[o] = 0.f;

    #pragma unroll 1
    for (int ch = 0; ch < NCHUNK; ++ch) {
        __syncthreads();
        STAGE_CHUNK(ch);
        __syncthreads();

        #pragma unroll
        for (int cc = 0; cc < CCH; ++cc) {
            const int c = ch * CCH + cc;
            float n[9];
            #pragma unroll
            for (int kh = 0; kh < 3; ++kh)
                #pragma unroll
                for (int kw = 0; kw < 3; ++kw)
                    n[kh * 3 + kw] = sx[cc * CPLANE + (ty + kh) * HALO_W + (tx + kw)];

            float dw = 0.f;
            #pragma unroll
            for (int k = 0; k < 9; ++k)
                dw = fmaf(n[k], swts[4096 + c * 36 + k * 4 + r1], dw);
            const float routed = dw > 0.f ? dw : 0.1f * dw;

            const float4* cwv = (const float4*)(swts + c * 64);  // uniform b128 broadcast
            #pragma unroll
            for (int q = 0; q < 16; ++q) {            // y statically indexed only
                const float4 w4 = cwv[q];
                y[q * 4 + 0] = fmaf(w4.x, routed, y[q * 4 + 0]);
                y[q * 4 + 1] = fmaf(w4.y, routed, y[q * 4 + 1]);
                y[q * 4 + 2] = fmaf(w4.z, routed, y[q * 4 + 2]);
                y[q * 4 + 3] = fmaf(w4.w, routed, y[q * 4 + 3]);
            }
        }
    }

    // --- epilogue: bias + CA branch (x center re-read) + store ---
    const int hh = h0 + ty;
    const int ww = w0 + tx;
    float* op = out + (size_t)b * Cx * HWx + hh * Wx + ww;
    const float* xp = xb + hh * Wx + ww;
    #pragma unroll
    for (int o = 0; o < Cx; ++o) {
        const float v = y[o] + convb[o] + xp[(size_t)o * HWx] * swts[6400 + o * 4 + r2];
        op[(size_t)o * HWx] = v;
    }
}

extern "C" void kernel_launch(void* const* d_in, const int* in_sizes, int n_in,
                              void* d_out, int out_size, void* d_ws, size_t ws_size,
                              hipStream_t stream) {
    const float* x0     = (const float*)d_in[0];
    const float* x_deg  = (const float*)d_in[1];
    const float* kw1    = (const float*)d_in[2];
    const float* kw2    = (const float*)d_in[3];
    const float* convw  = (const float*)d_in[4];
    const float* convb  = (const float*)d_in[5];
    const float* ca_w1  = (const float*)d_in[6];
    const float* ca_w2  = (const float*)d_in[7];
    const float* g1w    = (const float*)d_in[8];
    const float* g1b    = (const float*)d_in[9];
    const float* g2w    = (const float*)d_in[10];
    const float* g2b    = (const float*)d_in[11];
    float* outp = (float*)d_out;
    float* wsf  = (float*)d_ws;

    da_prep<<<Bx + 1, 256, 0, stream>>>(x_deg, kw1, kw2, convw, ca_w1, ca_w2,
                                        g1w, g2w, wsf);

    dim3 grid(Wx / TW, Hx / TH, Bx);   // 4 x 16 x 16 = 1024 blocks
    da_main<<<grid, 256, 0, stream>>>(x0, wsf, g1b, g2b, convb, outp);
}